// Round 11
// baseline (190.497 us; speedup 1.0000x reference)
//
#include <hip/hip_runtime.h>

// TrajectoryScore: truncated-exponential mixture scoring + segment sums.
// 64 segments x 100,000 obs. 153.6 MB read-only stream.
//
// v9: TWO-PASS SPLIT — the controlled experiment separating consume-weight
// from cache-state. Evidence: R4's async-LDS pipeline had guaranteed-in-ISA
// MLP (64-128 KB/CU outstanding) yet delivered 10 GB/s/CU; the R6 probe
// (light consume, possibly L3-hot) delivered 25 GB/s/CU. Forced-VGPR
// pipelines are unbuildable (allocator spills: R9/R10, VGPR stuck at 36).
//
// Pass 1 (probe-shaped, COLD): pure global grid-stride over 76,191 chunks of
// 63 f4 = 84 obs; light consume (~15 VALU + 1 shfl) computing per-obs squared
// chord distance s2; writes s2 [6.4M floats = 25.6 MB] to d_ws.
// Pass 2: streams s2 (25.6 MB), applies exp/log/div mixture eval (trivial
// compute chip-wide) + segment reduction + atomics.
//
// Pre-committed readout:
//   pass1 ~28-38 us -> light consume streams fast; total ~35-50 us (win).
//   pass1 ~55-65 us -> probe was a cache-hot artifact; 2.5 TB/s is the
//                      platform's cold-stream ceiling here -> ROOFLINE next.
// Assumes ws_size >= 25.6 MB (standard harness workspace).

constexpr int ELT_BATCH   = 64;
constexpr int OBS_PER_ELT = 100000;
constexpr int N_F4_TOTAL  = ELT_BATCH * OBS_PER_ELT * 3 / 4;   // 4,800,000 f4 per array
constexpr int CHUNK_F4    = 63;                                 // 63 f4 = 84 obs per wave-chunk
constexpr int CHUNK_OBS   = 84;
constexpr int N_CHUNKS    = (N_F4_TOTAL + CHUNK_F4 - 1) / CHUNK_F4;  // 76,191 (last: 30 f4 = 40 obs)
constexpr int BLOCK       = 256;
constexpr int P1_BLOCKS   = 1024;                               // probe's config: 4 blocks/CU
constexpr int P1_WAVES    = P1_BLOCKS * (BLOCK / 64);           // 4096 waves
constexpr int P2_BLOCKS_PER_SEG = 8;
constexpr int S2_F4_PER_SEG     = OBS_PER_ELT / 4;              // 25,000 float4 of s2 per segment

__device__ __forceinline__ float wave_reduce_sum(float v) {
    #pragma unroll
    for (int off = 32; off > 0; off >>= 1)
        v += __shfl_down(v, off, 64);
    return v;
}

// ---------------------------------------------------------------------------
// Pass 1: probe-shaped s2 streamer. Lane map identical to v2..v8 (verified):
// lane 3g -> obs 4g (A: q0+q1+q2) and obs 4g+1 (B: q3 + head(lane 3g+1));
// lane 3g+1 -> obs 4g+2 (q2+q3 + head(lane 3g+2)); lane 3g+2 -> obs 4g+3
// (q1+q2+q3). head(m1)=q0+q1, head(m2)=q0. Lane 63 masked (act<=63).
// ---------------------------------------------------------------------------
__device__ __forceinline__ void s2_chunk(
    const float4 a, const float4 b, const int c,
    const int lane, const int g, const bool m0, const bool m1,
    float* __restrict__ s2out)
{
    const float d0 = a.x - b.x, d1 = a.y - b.y, d2 = a.z - b.z, d3 = a.w - b.w;
    const float q0 = d0 * d0, q1 = d1 * d1, q2 = d2 * d2, q3 = d3 * d3;

    const float head = m1 ? (q0 + q1) : q0;
    const float hn   = __shfl_down(head, 1, 64);

    const float t12 = q1 + q2;
    const float s2A = m0 ? (q0 + t12) : (m1 ? (q2 + q3 + hn) : (t12 + q3));
    const float s2B = q3 + hn;

    const int act  = min(CHUNK_F4, N_F4_TOTAL - c * CHUNK_F4);  // 63, or 30 on final chunk
    const int base = c * CHUNK_OBS;
    const int offA = 4 * g + (m0 ? 0 : (m1 ? 2 : 3));

    if (lane < act)         s2out[base + offA]      = s2A;
    if (m0 && lane < act)   s2out[base + 4 * g + 1] = s2B;
}

__global__ __launch_bounds__(BLOCK) void TrajectoryScore_58145267253396_kernel(
    const float4* __restrict__ pred4,
    const float4* __restrict__ obs4,
    float*        __restrict__ s2out)
{
    const int tid   = threadIdx.x;
    const int lane  = tid & 63;
    const int gwave = blockIdx.x * (BLOCK / 64) + (tid >> 6);   // 0..4095

    const int  m  = lane % 3;
    const bool m0 = (m == 0);
    const bool m1 = (m == 1);
    const int  g  = lane / 3;

    // Clamped coalesced lane address for chunk c.
    auto addr = [&](int c) { return min(c * CHUNK_F4 + lane, N_F4_TOTAL - 1); };

    int c = gwave;
    // Main loop: two chunks per iteration, 4 batched loads (probe shape).
    for (; c + P1_WAVES < N_CHUNKS; c += 2 * P1_WAVES) {
        const int c1 = c + P1_WAVES;
        const int i0 = addr(c), i1 = addr(c1);
        const float4 a0 = pred4[i0], b0 = obs4[i0];
        const float4 a1 = pred4[i1], b1 = obs4[i1];
        s2_chunk(a0, b0, c,  lane, g, m0, m1, s2out);
        s2_chunk(a1, b1, c1, lane, g, m0, m1, s2out);
    }
    // Tail: at most one chunk per wave remains.
    for (; c < N_CHUNKS; c += P1_WAVES) {
        const int i0 = addr(c);
        const float4 a0 = pred4[i0], b0 = obs4[i0];
        s2_chunk(a0, b0, c, lane, g, m0, m1, s2out);
    }
}

// ---------------------------------------------------------------------------
// Pass 2: mixture eval + segment sums over the 25.6 MB s2 buffer.
// ---------------------------------------------------------------------------
__global__ __launch_bounds__(BLOCK) void TrajectoryScore_58145267253396_eval_kernel(
    const float* __restrict__ s2buf,
    const float* __restrict__ h_arr,
    const float* __restrict__ lam_arr,
    const float* __restrict__ th_arr,
    float*       __restrict__ out)
{
    const int seg = blockIdx.x / P2_BLOCKS_PER_SEG;
    const int blk = blockIdx.x % P2_BLOCKS_PER_SEG;
    const int tid = threadIdx.x;
    const int lane = tid & 63;
    const int wave = tid >> 6;

    // Wave-uniform per-segment params (identical formula chain to v2..v8).
    const float h      = h_arr[seg];
    const float lam    = lam_arr[seg];
    const float th     = th_arr[seg];
    const float inv_th = 1.0f / th;
    const float coef   = h * lam / (1.0f - __expf(-lam));
    const float omh    = 1.0f - h;
    const float nli    = -lam * inv_th;

    const float4* s2_4 = reinterpret_cast<const float4*>(s2buf) + seg * S2_F4_PER_SEG;

    float ll = 0.0f;
    float hs = 0.0f;

    auto eval1 = [&](float s2) {
        const float e  = __expf(nli * s2);
        const float ph = coef * e;
        const float p  = ph + omh;        // > omh > 0: log/div safe
        const float lp = __logf(p);
        const float po = ph / p;
        const bool  cl = (s2 < th);
        ll += cl ? lp : 0.0f;
        hs += (cl && po > 0.95f) ? po : 0.0f;
    };

    for (int i = blk * BLOCK + tid; i < S2_F4_PER_SEG; i += P2_BLOCKS_PER_SEG * BLOCK) {
        const float4 s = s2_4[i];
        eval1(s.x); eval1(s.y); eval1(s.z); eval1(s.w);
    }

    // Block reduction: 64-lane shuffle, then LDS across the 4 waves.
    ll = wave_reduce_sum(ll);
    hs = wave_reduce_sum(hs);

    __shared__ float sll[BLOCK / 64];
    __shared__ float shs[BLOCK / 64];
    if (lane == 0) { sll[wave] = ll; shs[wave] = hs; }
    __syncthreads();
    if (tid == 0) {
        float L = 0.0f, H = 0.0f;
        #pragma unroll
        for (int w = 0; w < BLOCK / 64; ++w) { L += sll[w]; H += shs[w]; }
        atomicAdd(&out[seg], L);
        atomicAdd(&out[ELT_BATCH + seg], H);
        atomicAdd(&out[2 * ELT_BATCH + seg], H);  // hits_raw == hits
    }
}

extern "C" void kernel_launch(void* const* d_in, const int* in_sizes, int n_in,
                              void* d_out, int out_size, void* d_ws, size_t ws_size,
                              hipStream_t stream) {
    const float4* pred4   = (const float4*)d_in[0];
    const float4* obs4    = (const float4*)d_in[1];
    const float*  h_arr   = (const float*)d_in[2];
    const float*  lam_arr = (const float*)d_in[3];
    const float*  th_arr  = (const float*)d_in[4];
    float* out  = (float*)d_out;
    float* s2ws = (float*)d_ws;   // needs 6.4M floats = 25.6 MB of workspace

    // Harness poisons d_out to 0xAA before timed replays — zero it ourselves.
    hipMemsetAsync(out, 0, out_size * sizeof(float), stream);

    // Pass 1: probe-shaped s2 streaming (cold read of the full 153.6 MB).
    TrajectoryScore_58145267253396_kernel<<<dim3(P1_BLOCKS), dim3(BLOCK), 0, stream>>>(
        pred4, obs4, s2ws);

    // Pass 2: mixture eval + segment sums (stream-ordered after pass 1).
    TrajectoryScore_58145267253396_eval_kernel<<<dim3(ELT_BATCH * P2_BLOCKS_PER_SEG),
                                                 dim3(BLOCK), 0, stream>>>(
        s2ws, h_arr, lam_arr, th_arr, out);
}